// Round 2
// baseline (110.207 us; speedup 1.0000x reference)
//
#include <hip/hip_runtime.h>

// WaveletLinear: y[b,o] = sum_i w[o,i] * (1 - s^2) * exp(-0.5 s^2),
//   s = (x[b,i] - t[o,i]) / (A_MIN + softplus(sr[o,i]) + EPS)
// Rework: u = K*s^2, K = 0.5*log2(e); e = exp2(-u);
//   y = sum w*e - (1/K) * sum w*(u*e)   (split accumulators E and U)
//
// R7: force packed FP32 math. R5/R6 evidence: VALUBusy pinned ~61%, busy-time
// ~32us regardless of occupancy (32%->54%) => issue-bound; measured ~150
// cyc/iter matches a SCALARIZED inner loop (~40 VALU inst), not the packed
// model (~104). Fix: inline-asm v_pk_fma_f32 / v_pk_mul_f32 with op_sel
// broadcasts (no splat movs):
//   - A2[i][o] = {nti, inv} 8B pair  -> op_sel picks inv(hi)/nti(lo)
//   - W2[i/2][o] = {w_i, w_i+1} pair -> op_sel:[J,..] broadcasts half J
// Per 2-elem group: 5 pk insts + 2 v_exp_f32 (floor). Also: parallel
// conflict-free epilogue (plane-major LDS, all 8 waves gather 1 b each).

#define WL_A_MIN 0.001f
#define WL_EPS   1e-8f

constexpr int WL_B = 512;
constexpr int WL_O = 1024;
constexpr int WL_I = 512;

// K = 0.5*log2(e); sqrt(K); 1/K; log2(e); ln(2)
#define WL_SQK  0.84932180553704583800f
#define WL_IK   1.38629436111989061883f
#define WL_L2E  1.44269504088896340736f
#define WL_LN2  0.69314718055994530942f

typedef float v2f __attribute__((ext_vector_type(2)));

struct P3 { float nti, inv, w; };          // prep-internal LDS staging

__device__ __forceinline__ float fast_exp2(float a) {
#if __has_builtin(__builtin_amdgcn_exp2f)
    return __builtin_amdgcn_exp2f(a);
#else
    return exp2f(a);
#endif
}
__device__ __forceinline__ float fast_log2(float a) {
#if __has_builtin(__builtin_amdgcn_logf)
    return __builtin_amdgcn_logf(a);
#else
    return __log2f(a);
#endif
}
__device__ __forceinline__ float fast_rcp(float a) {
#if __has_builtin(__builtin_amdgcn_rcpf)
    return __builtin_amdgcn_rcpf(a);
#else
    return 1.0f / a;
#endif
}

// ---- packed-step macro: one i (8 b) with w broadcast from half OS of PW ----
// s  = pk_fma(x, inv, nti)     inv = PA.hi, nti = PA.lo  (op_sel broadcasts)
// u  = pk_mul(s, s)
// e  = exp2(-u)                (trans, neg folded as src modifier)
// aE = pk_fma(w, e, aE)        w = PW.half[OS]
// t  = pk_mul(u, e)
// aU = pk_fma(w, t, aU)
#define WL_STEP(PA, PW, OS, XA, XB)                                            \
  do {                                                                         \
    v2f x01 = {(XA).x, (XA).y}, x23 = {(XA).z, (XA).w};                        \
    v2f x45 = {(XB).x, (XB).y}, x67 = {(XB).z, (XB).w};                        \
    v2f s0_, s1_, s2_, s3_, u0_, u1_, u2_, u3_;                                \
    v2f e0_, e1_, e2_, e3_, t0_, t1_, t2_, t3_;                                \
    asm("v_pk_fma_f32 %0, %1, %2, %2 op_sel:[0,1,0] op_sel_hi:[1,1,0]"         \
        : "=v"(s0_) : "v"(x01), "v"(PA));                                      \
    asm("v_pk_fma_f32 %0, %1, %2, %2 op_sel:[0,1,0] op_sel_hi:[1,1,0]"         \
        : "=v"(s1_) : "v"(x23), "v"(PA));                                      \
    asm("v_pk_fma_f32 %0, %1, %2, %2 op_sel:[0,1,0] op_sel_hi:[1,1,0]"         \
        : "=v"(s2_) : "v"(x45), "v"(PA));                                      \
    asm("v_pk_fma_f32 %0, %1, %2, %2 op_sel:[0,1,0] op_sel_hi:[1,1,0]"         \
        : "=v"(s3_) : "v"(x67), "v"(PA));                                      \
    asm("v_pk_mul_f32 %0, %1, %1" : "=v"(u0_) : "v"(s0_));                     \
    asm("v_pk_mul_f32 %0, %1, %1" : "=v"(u1_) : "v"(s1_));                     \
    asm("v_pk_mul_f32 %0, %1, %1" : "=v"(u2_) : "v"(s2_));                     \
    asm("v_pk_mul_f32 %0, %1, %1" : "=v"(u3_) : "v"(s3_));                     \
    e0_.x = fast_exp2(-u0_.x); e0_.y = fast_exp2(-u0_.y);                      \
    e1_.x = fast_exp2(-u1_.x); e1_.y = fast_exp2(-u1_.y);                      \
    e2_.x = fast_exp2(-u2_.x); e2_.y = fast_exp2(-u2_.y);                      \
    e3_.x = fast_exp2(-u3_.x); e3_.y = fast_exp2(-u3_.y);                      \
    asm("v_pk_fma_f32 %0, %1, %2, %0 op_sel:[" OS ",0,0] op_sel_hi:[" OS ",1,1]" \
        : "+v"(aE0) : "v"(PW), "v"(e0_));                                      \
    asm("v_pk_fma_f32 %0, %1, %2, %0 op_sel:[" OS ",0,0] op_sel_hi:[" OS ",1,1]" \
        : "+v"(aE1) : "v"(PW), "v"(e1_));                                      \
    asm("v_pk_fma_f32 %0, %1, %2, %0 op_sel:[" OS ",0,0] op_sel_hi:[" OS ",1,1]" \
        : "+v"(aE2) : "v"(PW), "v"(e2_));                                      \
    asm("v_pk_fma_f32 %0, %1, %2, %0 op_sel:[" OS ",0,0] op_sel_hi:[" OS ",1,1]" \
        : "+v"(aE3) : "v"(PW), "v"(e3_));                                      \
    asm("v_pk_mul_f32 %0, %1, %2" : "=v"(t0_) : "v"(u0_), "v"(e0_));           \
    asm("v_pk_mul_f32 %0, %1, %2" : "=v"(t1_) : "v"(u1_), "v"(e1_));           \
    asm("v_pk_mul_f32 %0, %1, %2" : "=v"(t2_) : "v"(u2_), "v"(e2_));           \
    asm("v_pk_mul_f32 %0, %1, %2" : "=v"(t3_) : "v"(u3_), "v"(e3_));           \
    asm("v_pk_fma_f32 %0, %1, %2, %0 op_sel:[" OS ",0,0] op_sel_hi:[" OS ",1,1]" \
        : "+v"(aU0) : "v"(PW), "v"(t0_));                                      \
    asm("v_pk_fma_f32 %0, %1, %2, %0 op_sel:[" OS ",0,0] op_sel_hi:[" OS ",1,1]" \
        : "+v"(aU1) : "v"(PW), "v"(t1_));                                      \
    asm("v_pk_fma_f32 %0, %1, %2, %0 op_sel:[" OS ",0,0] op_sel_hi:[" OS ",1,1]" \
        : "+v"(aU2) : "v"(PW), "v"(t2_));                                      \
    asm("v_pk_fma_f32 %0, %1, %2, %0 op_sel:[" OS ",0,0] op_sel_hi:[" OS ",1,1]" \
        : "+v"(aU3) : "v"(PW), "v"(t3_));                                      \
  } while (0)

// Param precompute. Block = 256 thr handles a 64(o) x 16(i) tile.
// Phase 1: coalesced float4 reads, compute, store P3 into LDS (transpose).
// Phase 2: lane=o writes A2[i][o]={nti,inv} (dwordx2, 512B/wave) and
// W2[i/2][o]={w_i,w_i+1} (dwordx2, 512B/wave).
__global__ __launch_bounds__(256) void wl_prep(
    const float* __restrict__ translation,
    const float* __restrict__ scale_raw,
    const float* __restrict__ weights,
    v2f* __restrict__ A2,
    v2f* __restrict__ W2)
{
    __shared__ P3 lds[16 * 64];                        // 12 KB  [i_l][o_l]
    const int t  = threadIdx.x;
    const int o0 = blockIdx.x * 64;
    const int i0 = blockIdx.y * 16;

    {
        const int o_l = t >> 2;                        // 0..63
        const int iq  = t & 3;                         // 0..3 -> 4 i each
        const size_t g = (size_t)(o0 + o_l) * WL_I + (i0 + iq * 4);
        const float4 tv = *reinterpret_cast<const float4*>(translation + g);
        const float4 sv = *reinterpret_cast<const float4*>(scale_raw   + g);
        const float4 wv = *reinterpret_cast<const float4*>(weights     + g);
        const float tt[4] = {tv.x, tv.y, tv.z, tv.w};
        const float ss[4] = {sv.x, sv.y, sv.z, sv.w};
        const float ww[4] = {wv.x, wv.y, wv.z, wv.w};
        #pragma unroll
        for (int j = 0; j < 4; ++j) {
            float ex  = fast_exp2(ss[j] * WL_L2E);     // softplus via hw exp2/log2
            float sp  = fast_log2(1.0f + ex) * WL_LN2;
            float inv = fast_rcp(WL_A_MIN + sp + WL_EPS) * WL_SQK;
            P3 pv; pv.nti = -tt[j] * inv; pv.inv = inv; pv.w = ww[j];
            lds[(iq * 4 + j) * 64 + o_l] = pv;
        }
    }
    __syncthreads();
    {
        const int o_l = t & 63;
        const int r   = t >> 6;                        // 0..3
        const int o   = o0 + o_l;
        #pragma unroll
        for (int jp = 0; jp < 2; ++jp) {
            const int i_l = r * 4 + jp * 2;            // even
            P3 a = lds[i_l * 64 + o_l];
            P3 b = lds[(i_l + 1) * 64 + o_l];
            A2[(size_t)(i0 + i_l)     * WL_O + o] = (v2f){a.nti, a.inv};
            A2[(size_t)(i0 + i_l + 1) * WL_O + o] = (v2f){b.nti, b.inv};
            W2[(size_t)((i0 + i_l) >> 1) * WL_O + o] = (v2f){a.w, b.w};
        }
    }
}

// Main: grid (O/64=16, B/8=64) = 1024 blocks, 512 thr = 8 waves.
// Wave wid = i-eighth (64 i = 32 pair-groups); covers all 8 b of the tile.
// gx-major linear ids -> o-slab pinned to one XCD's L2 (param reuse).
__global__ __launch_bounds__(512, 6) void wl_main(
    const float* __restrict__ x,
    const v2f* __restrict__ A2,
    const v2f* __restrict__ W2,
    float* __restrict__ out)
{
    __shared__ float smem[16 * 513];                   // 32.8 KB (xT uses 16 KB)

    const int tid  = threadIdx.x;
    const int lane = tid & 63;
    const int wid  = tid >> 6;                         // 0..7 = i-eighth
    const int o    = blockIdx.x * 64 + lane;
    const int b0   = blockIdx.y * 8;

    // ---- stage x^T once: xT[i*8 + b_l]; one wave per b-row, coalesced ----
    {
        const int b_l = tid & 7;
        const int seg = tid >> 3;                      // 0..63 -> i in [seg*8,+8)
        const float* xg = &x[(size_t)(b0 + b_l) * WL_I + seg * 8];
        const float4 v0 = *reinterpret_cast<const float4*>(xg);
        const float4 v1 = *reinterpret_cast<const float4*>(xg + 4);
        const int base = seg * 64 + b_l;
        smem[base +  0] = v0.x;
        smem[base +  8] = v0.y;
        smem[base + 16] = v0.z;
        smem[base + 24] = v0.w;
        smem[base + 32] = v1.x;
        smem[base + 40] = v1.y;
        smem[base + 48] = v1.z;
        smem[base + 56] = v1.w;
    }
    __syncthreads();

    const v2f* __restrict__ pA = A2 + (size_t)(wid * 64) * WL_O + o;
    const v2f* __restrict__ pW = W2 + (size_t)(wid * 32) * WL_O + o;
    const float* xr = &smem[wid * 64 * 8];             // uniform per wave

    v2f aE0 = {0.f,0.f}, aE1 = {0.f,0.f}, aE2 = {0.f,0.f}, aE3 = {0.f,0.f};
    v2f aU0 = {0.f,0.f}, aU1 = {0.f,0.f}, aU2 = {0.f,0.f}, aU3 = {0.f,0.f};

    #pragma unroll 2
    for (int g = 0; g < 32; ++g) {                     // 2 i per group
        const v2f pa0 = pA[0];
        const v2f pa1 = pA[WL_O];
        const v2f pw  = pW[0];
        pA += 2 * WL_O;  pW += WL_O;
        const float4 xa0 = ((const float4*)xr)[0];     // i,   b0..3 (broadcast)
        const float4 xb0 = ((const float4*)xr)[1];     // i,   b4..7
        const float4 xa1 = ((const float4*)xr)[2];     // i+1, b0..3
        const float4 xb1 = ((const float4*)xr)[3];     // i+1, b4..7
        xr += 16;
        WL_STEP(pa0, pw, "0", xa0, xb0);
        WL_STEP(pa1, pw, "1", xa1, xb1);
    }

    // ---- parallel epilogue: plane-major dump (conflict-free), 1 b per wave ----
    __syncthreads();                                   // done reading xT
    {
        const int c = wid * 64 + lane;                 // 0..511
        const float vals[16] = {aE0.x,aE0.y,aE1.x,aE1.y,aE2.x,aE2.y,aE3.x,aE3.y,
                                aU0.x,aU0.y,aU1.x,aU1.y,aU2.x,aU2.y,aU3.x,aU3.y};
        #pragma unroll
        for (int k = 0; k < 16; ++k)
            smem[k * 513 + c] = vals[k];               // lane-stride 4B: conflict-free
    }
    __syncthreads();
    {
        // wave wid handles b = b0 + wid (plane wid = E[b], plane 8+wid = U[b])
        float E = 0.f, U = 0.f;
        #pragma unroll
        for (int sw = 0; sw < 8; ++sw) {
            E += smem[wid * 513       + sw * 64 + lane];
            U += smem[(8 + wid) * 513 + sw * 64 + lane];
        }
        out[(size_t)(b0 + wid) * WL_O + o] = fmaf(-WL_IK, U, E);
    }
}

extern "C" void kernel_launch(void* const* d_in, const int* in_sizes, int n_in,
                              void* d_out, int out_size, void* d_ws, size_t ws_size,
                              hipStream_t stream) {
    const float* x           = (const float*)d_in[0];
    const float* translation = (const float*)d_in[1];
    const float* scale_raw   = (const float*)d_in[2];
    const float* weights     = (const float*)d_in[3];
    float*       out         = (float*)d_out;
    // workspace: A2 pairs {nti,inv} 4.19MB, then W2 pairs {w_i,w_i+1} 2.10MB
    v2f* A2 = (v2f*)d_ws;
    v2f* W2 = (v2f*)((char*)d_ws + (size_t)WL_I * WL_O * sizeof(v2f));

    wl_prep<<<dim3(WL_O / 64, WL_I / 16), dim3(256), 0, stream>>>(
        translation, scale_raw, weights, A2, W2);

    wl_main<<<dim3(WL_O / 64, WL_B / 8), dim3(512), 0, stream>>>(
        x, A2, W2, out);
}

// Round 3
// 107.097 us; speedup vs baseline: 1.0290x; 1.0290x over previous
//
#include <hip/hip_runtime.h>

// WaveletLinear: y[b,o] = sum_i w[o,i] * (1 - s^2) * exp(-0.5 s^2),
//   s = (x[b,i] - t[o,i]) / (A_MIN + softplus(sr[o,i]) + EPS)
// Rework: u = K*s'^2 with s' = s*sqrt(K), K = 0.5*log2(e); e2 = exp2(-u);
//   y = sum_i (mwk*u + w) * e2,  mwk = -w/K     <- single-accumulator form
//
// R8: cut FP32 lane-ops 5 -> 4 per element. R7 proved v_pk_f32 gives NO pipe
// gain on CDNA4 (FP32 pipe = 1 FMA/lane/cyc packed or not; forced-pk == 
// compiler code at ~160 cyc/step). So reduce ops: fold w into the polynomial:
//   v' = pk_fma(mwk, u, w)   (mwk,w broadcast from a pair via op_sel)
//   acc = pk_fma(v', e, acc)
// Per i-step (8 b): 16 pk + 1 mul + 8 exp  (~130 cyc) vs R7 20 pk + 8 exp
// (~160 measured). Also: single acc set (-8 VGPR), epilogue halves (8 planes),
// LDS 33.3 -> 16.5 KB (R7's LDS bump cost 10 occupancy pts). ws stays 6.3 MB:
// {nti,inv} pairs + w; mwk built in-kernel (1 v_mul/step, literal in src0).

#define WL_A_MIN 0.001f
#define WL_EPS   1e-8f

constexpr int WL_B = 512;
constexpr int WL_O = 1024;
constexpr int WL_I = 512;

// K = 0.5*log2(e); sqrt(K); 1/K; log2(e); ln(2)
#define WL_SQK  0.84932180553704583800f
#define WL_IK   1.38629436111989061883f
#define WL_L2E  1.44269504088896340736f
#define WL_LN2  0.69314718055994530942f

typedef float v2f __attribute__((ext_vector_type(2)));

struct P3 { float nti, inv, w; };          // prep-internal LDS staging

__device__ __forceinline__ float fast_exp2(float a) {
#if __has_builtin(__builtin_amdgcn_exp2f)
    return __builtin_amdgcn_exp2f(a);
#else
    return exp2f(a);
#endif
}
__device__ __forceinline__ float fast_log2(float a) {
#if __has_builtin(__builtin_amdgcn_logf)
    return __builtin_amdgcn_logf(a);
#else
    return __log2f(a);
#endif
}
__device__ __forceinline__ float fast_rcp(float a) {
#if __has_builtin(__builtin_amdgcn_rcpf)
    return __builtin_amdgcn_rcpf(a);
#else
    return 1.0f / a;
#endif
}

// ---- packed-step: one i (8 b).  PA={nti,inv}, PW={w,mwk} (op_sel bcast) ----
// s   = pk_fma(x, PA.hi, PA.lo)        (inv, nti)
// u   = pk_mul(s, s)
// e   = exp2(-u)                        (trans, neg as src modifier)
// v'  = pk_fma(PW.hi, u, PW.lo)        (mwk*u + w)
// acc = pk_fma(v', e, acc)
#define WL_STEP(PA, PW, XA, XB)                                                \
  do {                                                                         \
    v2f x01 = {(XA).x, (XA).y}, x23 = {(XA).z, (XA).w};                        \
    v2f x45 = {(XB).x, (XB).y}, x67 = {(XB).z, (XB).w};                        \
    v2f s0_, s1_, s2_, s3_, u0_, u1_, u2_, u3_;                                \
    v2f e0_, e1_, e2_, e3_, v0_, v1_, v2_, v3_;                                \
    asm("v_pk_fma_f32 %0, %1, %2, %2 op_sel:[0,1,0] op_sel_hi:[1,1,0]"         \
        : "=v"(s0_) : "v"(x01), "v"(PA));                                      \
    asm("v_pk_fma_f32 %0, %1, %2, %2 op_sel:[0,1,0] op_sel_hi:[1,1,0]"         \
        : "=v"(s1_) : "v"(x23), "v"(PA));                                      \
    asm("v_pk_fma_f32 %0, %1, %2, %2 op_sel:[0,1,0] op_sel_hi:[1,1,0]"         \
        : "=v"(s2_) : "v"(x45), "v"(PA));                                      \
    asm("v_pk_fma_f32 %0, %1, %2, %2 op_sel:[0,1,0] op_sel_hi:[1,1,0]"         \
        : "=v"(s3_) : "v"(x67), "v"(PA));                                      \
    asm("v_pk_mul_f32 %0, %1, %1" : "=v"(u0_) : "v"(s0_));                     \
    asm("v_pk_mul_f32 %0, %1, %1" : "=v"(u1_) : "v"(s1_));                     \
    asm("v_pk_mul_f32 %0, %1, %1" : "=v"(u2_) : "v"(s2_));                     \
    asm("v_pk_mul_f32 %0, %1, %1" : "=v"(u3_) : "v"(s3_));                     \
    e0_.x = fast_exp2(-u0_.x); e0_.y = fast_exp2(-u0_.y);                      \
    e1_.x = fast_exp2(-u1_.x); e1_.y = fast_exp2(-u1_.y);                      \
    e2_.x = fast_exp2(-u2_.x); e2_.y = fast_exp2(-u2_.y);                      \
    e3_.x = fast_exp2(-u3_.x); e3_.y = fast_exp2(-u3_.y);                      \
    asm("v_pk_fma_f32 %0, %1, %2, %1 op_sel:[1,0,0] op_sel_hi:[1,1,0]"         \
        : "=v"(v0_) : "v"(PW), "v"(u0_));                                      \
    asm("v_pk_fma_f32 %0, %1, %2, %1 op_sel:[1,0,0] op_sel_hi:[1,1,0]"         \
        : "=v"(v1_) : "v"(PW), "v"(u1_));                                      \
    asm("v_pk_fma_f32 %0, %1, %2, %1 op_sel:[1,0,0] op_sel_hi:[1,1,0]"         \
        : "=v"(v2_) : "v"(PW), "v"(u2_));                                      \
    asm("v_pk_fma_f32 %0, %1, %2, %1 op_sel:[1,0,0] op_sel_hi:[1,1,0]"         \
        : "=v"(v3_) : "v"(PW), "v"(u3_));                                      \
    asm("v_pk_fma_f32 %0, %1, %2, %0" : "+v"(acc0) : "v"(v0_), "v"(e0_));      \
    asm("v_pk_fma_f32 %0, %1, %2, %0" : "+v"(acc1) : "v"(v1_), "v"(e1_));      \
    asm("v_pk_fma_f32 %0, %1, %2, %0" : "+v"(acc2) : "v"(v2_), "v"(e2_));      \
    asm("v_pk_fma_f32 %0, %1, %2, %0" : "+v"(acc3) : "v"(v3_), "v"(e3_));      \
  } while (0)

// Param precompute. Block = 256 thr handles a 64(o) x 16(i) tile.
// Phase 1: coalesced float4 reads, compute, store P3 into LDS (transpose).
// Phase 2: lane=o writes A2[i][o]={nti,inv} (dwordx2) and W1[i][o]=w (dword).
__global__ __launch_bounds__(256) void wl_prep(
    const float* __restrict__ translation,
    const float* __restrict__ scale_raw,
    const float* __restrict__ weights,
    v2f* __restrict__ A2,
    float* __restrict__ W1)
{
    __shared__ P3 lds[16 * 64];                        // 12 KB  [i_l][o_l]
    const int t  = threadIdx.x;
    const int o0 = blockIdx.x * 64;
    const int i0 = blockIdx.y * 16;

    {
        const int o_l = t >> 2;                        // 0..63
        const int iq  = t & 3;                         // 0..3 -> 4 i each
        const size_t g = (size_t)(o0 + o_l) * WL_I + (i0 + iq * 4);
        const float4 tv = *reinterpret_cast<const float4*>(translation + g);
        const float4 sv = *reinterpret_cast<const float4*>(scale_raw   + g);
        const float4 wv = *reinterpret_cast<const float4*>(weights     + g);
        const float tt[4] = {tv.x, tv.y, tv.z, tv.w};
        const float ss[4] = {sv.x, sv.y, sv.z, sv.w};
        const float ww[4] = {wv.x, wv.y, wv.z, wv.w};
        #pragma unroll
        for (int j = 0; j < 4; ++j) {
            float ex  = fast_exp2(ss[j] * WL_L2E);     // softplus via hw exp2/log2
            float sp  = fast_log2(1.0f + ex) * WL_LN2;
            float inv = fast_rcp(WL_A_MIN + sp + WL_EPS) * WL_SQK;
            P3 pv; pv.nti = -tt[j] * inv; pv.inv = inv; pv.w = ww[j];
            lds[(iq * 4 + j) * 64 + o_l] = pv;
        }
    }
    __syncthreads();
    {
        const int o_l = t & 63;
        const int r   = t >> 6;                        // 0..3 -> 4 i each
        const int o   = o0 + o_l;
        #pragma unroll
        for (int j = 0; j < 4; ++j) {
            const int i_l = r * 4 + j;
            P3 a = lds[i_l * 64 + o_l];
            A2[(size_t)(i0 + i_l) * WL_O + o] = (v2f){a.nti, a.inv};
            W1[(size_t)(i0 + i_l) * WL_O + o] = a.w;
        }
    }
}

// Main: grid (O/64=16, B/8=64) = 1024 blocks, 512 thr = 8 waves.
// Wave wid = i-eighth (64 i); covers all 8 b of the tile.
// gx-major linear ids -> o-slab pinned to one XCD's L2 (param reuse).
__global__ __launch_bounds__(512, 8) void wl_main(
    const float* __restrict__ x,
    const v2f* __restrict__ A2,
    const float* __restrict__ W1,
    float* __restrict__ out)
{
    __shared__ float smem[8 * 513];                    // 16.4 KB (xT uses 16 KB)

    const int tid  = threadIdx.x;
    const int lane = tid & 63;
    const int wid  = tid >> 6;                         // 0..7 = i-eighth
    const int o    = blockIdx.x * 64 + lane;
    const int b0   = blockIdx.y * 8;

    // ---- stage x^T once: xT[i*8 + b_l]; one wave per b-row, coalesced ----
    {
        const int b_l = tid & 7;
        const int seg = tid >> 3;                      // 0..63 -> i in [seg*8,+8)
        const float* xg = &x[(size_t)(b0 + b_l) * WL_I + seg * 8];
        const float4 v0 = *reinterpret_cast<const float4*>(xg);
        const float4 v1 = *reinterpret_cast<const float4*>(xg + 4);
        const int base = seg * 64 + b_l;
        smem[base +  0] = v0.x;
        smem[base +  8] = v0.y;
        smem[base + 16] = v0.z;
        smem[base + 24] = v0.w;
        smem[base + 32] = v1.x;
        smem[base + 40] = v1.y;
        smem[base + 48] = v1.z;
        smem[base + 56] = v1.w;
    }
    __syncthreads();

    const v2f*   __restrict__ pA = A2 + (size_t)(wid * 64) * WL_O + o;
    const float* __restrict__ pW = W1 + (size_t)(wid * 64) * WL_O + o;
    const float* xr = &smem[wid * 64 * 8];             // uniform per wave

    v2f acc0 = {0.f,0.f}, acc1 = {0.f,0.f}, acc2 = {0.f,0.f}, acc3 = {0.f,0.f};

    #pragma unroll 4
    for (int ii = 0; ii < 64; ++ii) {
        const v2f   pa = *pA;  pA += WL_O;             // {nti, inv}  512B/wave
        v2f pw;
        pw.x = *pW;  pW += WL_O;                       // w           256B/wave
        pw.y = pw.x * (-WL_IK);                        // mwk = -w/K  (1 v_mul)
        const float4 xa = ((const float4*)xr)[0];      // b0..3 (broadcast)
        const float4 xb = ((const float4*)xr)[1];      // b4..7 (broadcast)
        xr += 8;
        WL_STEP(pa, pw, xa, xb);
    }

    // ---- parallel epilogue: plane-major dump (conflict-free), 1 b per wave ----
    __syncthreads();                                   // done reading xT
    {
        const int c = wid * 64 + lane;                 // 0..511
        const float vals[8] = {acc0.x, acc0.y, acc1.x, acc1.y,
                               acc2.x, acc2.y, acc3.x, acc3.y};
        #pragma unroll
        for (int k = 0; k < 8; ++k)
            smem[k * 513 + c] = vals[k];               // lane-stride 4B: conflict-free
    }
    __syncthreads();
    {
        // wave wid handles b = b0 + wid (plane wid = y[b] partials)
        float y = 0.f;
        #pragma unroll
        for (int sw = 0; sw < 8; ++sw)
            y += smem[wid * 513 + sw * 64 + lane];
        out[(size_t)(b0 + wid) * WL_O + o] = y;
    }
}

extern "C" void kernel_launch(void* const* d_in, const int* in_sizes, int n_in,
                              void* d_out, int out_size, void* d_ws, size_t ws_size,
                              hipStream_t stream) {
    const float* x           = (const float*)d_in[0];
    const float* translation = (const float*)d_in[1];
    const float* scale_raw   = (const float*)d_in[2];
    const float* weights     = (const float*)d_in[3];
    float*       out         = (float*)d_out;
    // workspace: A2 pairs {nti,inv} 4.19MB, then W1 floats 2.10MB (6.3MB total)
    v2f*   A2 = (v2f*)d_ws;
    float* W1 = (float*)((char*)d_ws + (size_t)WL_I * WL_O * sizeof(v2f));

    wl_prep<<<dim3(WL_O / 64, WL_I / 16), dim3(256), 0, stream>>>(
        translation, scale_raw, weights, A2, W1);

    wl_main<<<dim3(WL_O / 64, WL_B / 8), dim3(512), 0, stream>>>(
        x, A2, W1, out);
}